// Round 3
// baseline (1212.756 us; speedup 1.0000x reference)
//
#include <hip/hip_runtime.h>

#define BATCH   8
#define CDIM    96
#define LSEQ    4096
#define DIN     192
#define DTR     6
#define DST     16
#define NCHUNK  64
#define CLEN    64
#define BL      (BATCH*LSEQ)

typedef unsigned short u16;

__device__ __forceinline__ float b2f(u16 u) {
    union { unsigned int i; float f; } v; v.i = ((unsigned int)u) << 16; return v.f;
}
__device__ __forceinline__ u16 f2b(float f) {
    union { float f; unsigned int i; } v; v.f = f;
    unsigned int x = v.i;
    return (u16)((x + 0x7fffu + ((x >> 16) & 1u)) >> 16);
}
__device__ __forceinline__ float silu_f(float x) { return x / (1.0f + expf(-x)); }
__device__ __forceinline__ float softplus_f(float x) {
    // branch-free, overflow-proof: max(x,0) + log1p(exp(-|x|))
    return fmaxf(x, 0.0f) + log1pf(expf(-fabsf(x)));
}
__device__ __forceinline__ void dot4(const float4 w, const float* uv, float& acc) {
    acc = fmaf(uv[0], w.x, acc);
    acc = fmaf(uv[1], w.y, acc);
    acc = fmaf(uv[2], w.z, acc);
    acc = fmaf(uv[3], w.w, acc);
}

// K1: in_proj (x-half) + causal depthwise conv(4) + silu -> xc (bf16).
// grid (L/64, B), block 256. Tile: 64 rows + 3 halo. LDS ~52 KB.
__global__ __launch_bounds__(256) void k1_inproj_conv(
    const float* __restrict__ x,    // (8,96,4096) fp32
    const float* __restrict__ ipw,  // (384,96) fp32
    const float* __restrict__ cvw,  // (192,4) fp32
    const float* __restrict__ cvb,  // (192) fp32
    u16* __restrict__ xc)           // (BL,192) out: silu(conv(xm)) bf16
{
    __shared__ float u_lds[67 * 97];
    __shared__ u16 xm_lds[67 * 192];
    const int b = blockIdx.y;
    const int l0 = blockIdx.x * 64;
    const int tid = threadIdx.x;

    for (int idx = tid; idx < CDIM * 67; idx += 256) {
        int c = idx / 67, row = idx % 67;
        int l = l0 + row - 3;
        u_lds[row * 97 + c] = (l >= 0) ? x[((size_t)b * CDIM + c) * LSEQ + l] : 0.0f;
    }
    __syncthreads();

    // GEMM: rows 0..66, cols 0..191 (x-half of in_proj), K=96
    for (int idx = tid; idx < 67 * 48; idx += 256) {
        int row = idx / 48, cg = idx % 48;
        int col = cg * 4;
        const float4* w0 = (const float4*)(ipw + (size_t)(col + 0) * 96);
        const float4* w1 = (const float4*)(ipw + (size_t)(col + 1) * 96);
        const float4* w2 = (const float4*)(ipw + (size_t)(col + 2) * 96);
        const float4* w3 = (const float4*)(ipw + (size_t)(col + 3) * 96);
        const float* ur = &u_lds[row * 97];
        float a0 = 0, a1 = 0, a2 = 0, a3 = 0;
        #pragma unroll
        for (int kk = 0; kk < 24; ++kk) {
            float uv[4];
            #pragma unroll
            for (int i = 0; i < 4; ++i) uv[i] = ur[kk * 4 + i];
            dot4(w0[kk], uv, a0);
            dot4(w1[kk], uv, a1);
            dot4(w2[kk], uv, a2);
            dot4(w3[kk], uv, a3);
        }
        xm_lds[row * 192 + col + 0] = f2b(a0);
        xm_lds[row * 192 + col + 1] = f2b(a1);
        xm_lds[row * 192 + col + 2] = f2b(a2);
        xm_lds[row * 192 + col + 3] = f2b(a3);
    }
    __syncthreads();

    // causal conv(4) + bias + silu
    for (int idx = tid; idx < 64 * DIN; idx += 256) {
        int lr = idx / DIN, ch = idx % DIN;
        float acc = cvb[ch];
        acc = fmaf(cvw[ch * 4 + 0], b2f(xm_lds[(lr + 0) * 192 + ch]), acc);
        acc = fmaf(cvw[ch * 4 + 1], b2f(xm_lds[(lr + 1) * 192 + ch]), acc);
        acc = fmaf(cvw[ch * 4 + 2], b2f(xm_lds[(lr + 2) * 192 + ch]), acc);
        acc = fmaf(cvw[ch * 4 + 3], b2f(xm_lds[(lr + 3) * 192 + ch]), acc);
        xc[((size_t)b * LSEQ + l0 + lr) * DIN + ch] = f2b(silu_f(acc));
    }
}

// K2: x_proj: per row (b,l): 38 dots of K=192 -> dt(6), B(16), C(16).
__global__ __launch_bounds__(256) void k2_xproj(
    const u16* __restrict__ xc,
    const float* __restrict__ xpw,  // (38,192) fp32
    float* __restrict__ dtb,        // (BL,6)
    float* __restrict__ bcb)        // (BL,32) [B(16) | C(16)]
{
    const int lane = threadIdx.x & 63;
    const int wv = threadIdx.x >> 6;
    const int row = blockIdx.x * 4 + wv;
    const u16* xr = xc + (size_t)row * DIN;
    float x0 = b2f(xr[lane]), x1 = b2f(xr[lane + 64]), x2 = b2f(xr[lane + 128]);
    for (int o = 0; o < 38; ++o) {
        const float* w = xpw + (size_t)o * DIN;
        float s = x0 * w[lane] + x1 * w[lane + 64] + x2 * w[lane + 128];
        #pragma unroll
        for (int m = 32; m >= 1; m >>= 1) s += __shfl_xor(s, m, 64);
        if (lane == 0) {
            if (o < DTR)            dtb[(size_t)row * DTR + o] = s;
            else if (o < DTR + DST) bcb[(size_t)row * 32 + (o - DTR)] = s;
            else                    bcb[(size_t)row * 32 + 16 + (o - DTR - DST)] = s;
        }
    }
}

// K3 (pass A): chunk-local scan with h0=0 -> ph[P(16) | hend(16)].
__global__ __launch_bounds__(192) void k3_scan_partial(
    const u16* __restrict__ xc,
    const float* __restrict__ dtbuf,
    const float* __restrict__ bcb,
    const float* __restrict__ dpw,   // (192,6) fp32
    const float* __restrict__ dpb,   // (192) fp32
    const float* __restrict__ alog,  // (192,16) fp32
    float* __restrict__ ph)          // (B,NCHUNK,192,32)
{
    __shared__ float dts[CLEN * 6];
    __shared__ float bcs[CLEN * 32];
    const int b = blockIdx.y, s = blockIdx.x;
    const int e = threadIdx.x;
    const size_t rb = (size_t)b * LSEQ + s * CLEN;
    for (int i = e; i < CLEN * 6; i += 192)  dts[i] = dtbuf[rb * 6 + i];
    for (int i = e; i < CLEN * 32; i += 192) bcs[i] = bcb[rb * 32 + i];
    float wr[6];
    #pragma unroll
    for (int r = 0; r < 6; ++r) wr[r] = dpw[e * 6 + r];
    const float bias = dpb[e];
    float m[DST];
    #pragma unroll
    for (int n = 0; n < DST; ++n) m[n] = -expf(alog[e * DST + n]);
    float h[DST], P[DST];
    #pragma unroll
    for (int n = 0; n < DST; ++n) { h[n] = 0.0f; P[n] = 1.0f; }
    __syncthreads();
    for (int j = 0; j < CLEN; ++j) {
        float u = b2f(xc[(rb + j) * DIN + e]);
        float xdt = bias;
        #pragma unroll
        for (int r = 0; r < 6; ++r) xdt = fmaf(dts[j * 6 + r], wr[r], xdt);
        float delta = softplus_f(xdt);
        float du = delta * u;
        #pragma unroll
        for (int n = 0; n < DST; ++n) {
            float dA = expf(delta * m[n]);
            h[n] = fmaf(dA, h[n], du * bcs[j * 32 + n]);
            P[n] *= dA;
        }
    }
    float* o = ph + (((size_t)b * NCHUNK + s) * 192 + e) * 32;
    #pragma unroll
    for (int n = 0; n < DST; ++n) { o[n] = P[n]; o[16 + n] = h[n]; }
}

// K4 (pass B): sequential chunk combine per (b,e,n); overwrites ph's P-slot
// with the state at chunk START (in-place, read-before-write per thread).
__global__ __launch_bounds__(256) void k4_combine(float* __restrict__ ph)
{
    int g = blockIdx.x * 256 + threadIdx.x;
    int b = g / (192 * DST);
    int rem = g % (192 * DST);
    int e = rem / DST, n = rem % DST;
    float h = 0.0f;
    for (int s = 0; s < NCHUNK; ++s) {
        size_t ix = ((size_t)(b * NCHUNK + s) * 192 + e) * 32;
        float P = ph[ix + n];
        float hend = ph[ix + 16 + n];
        ph[ix + n] = h;               // h at chunk start
        h = fmaf(P, h, hend);
    }
}

// K5 (pass C): full scan with correct h_init; writes yraw = y + u*D in-place
// over xc (bf16).
__global__ __launch_bounds__(192) void k5_scan_final(
    u16* __restrict__ xc,               // in: u, out: yraw
    const float* __restrict__ dtbuf,
    const float* __restrict__ bcb,
    const float* __restrict__ dpw,
    const float* __restrict__ dpb,
    const float* __restrict__ alog,
    const float* __restrict__ Dp,       // (192)
    const float* __restrict__ ph)       // [hin(16) | hend(16)]
{
    __shared__ float dts[CLEN * 6];
    __shared__ float bcs[CLEN * 32];
    const int b = blockIdx.y, s = blockIdx.x;
    const int e = threadIdx.x;
    const size_t rb = (size_t)b * LSEQ + s * CLEN;
    for (int i = e; i < CLEN * 6; i += 192)  dts[i] = dtbuf[rb * 6 + i];
    for (int i = e; i < CLEN * 32; i += 192) bcs[i] = bcb[rb * 32 + i];
    float wr[6];
    #pragma unroll
    for (int r = 0; r < 6; ++r) wr[r] = dpw[e * 6 + r];
    const float bias = dpb[e];
    const float De = Dp[e];
    float m[DST];
    #pragma unroll
    for (int n = 0; n < DST; ++n) m[n] = -expf(alog[e * DST + n]);
    float h[DST];
    const float* hi = ph + (((size_t)b * NCHUNK + s) * 192 + e) * 32;
    #pragma unroll
    for (int n = 0; n < DST; ++n) h[n] = hi[n];
    __syncthreads();
    for (int j = 0; j < CLEN; ++j) {
        float u = b2f(xc[(rb + j) * DIN + e]);
        float xdt = bias;
        #pragma unroll
        for (int r = 0; r < 6; ++r) xdt = fmaf(dts[j * 6 + r], wr[r], xdt);
        float delta = softplus_f(xdt);
        float du = delta * u;
        float y = 0.0f;
        #pragma unroll
        for (int n = 0; n < DST; ++n) {
            float dA = expf(delta * m[n]);
            h[n] = fmaf(dA, h[n], du * bcs[j * 32 + n]);
            y = fmaf(h[n], bcs[j * 32 + 16 + n], y);
        }
        xc[(rb + j) * DIN + e] = f2b(y + u * De);
    }
}

// K6: recompute z = in_proj z-half, gate yraw*silu(z), out_proj GEMM (K=192),
// LayerNorm(96), transposed fp32 store. grid (L/32, B), block 256. LDS ~50 KB.
__global__ __launch_bounds__(256) void k6_gate_outproj_ln(
    const float* __restrict__ x,          // (8,96,4096) fp32
    const float* __restrict__ ipw,        // (384,96) fp32
    const u16* __restrict__ yraw,         // (BL,192) bf16
    const float* __restrict__ opw,        // (96,192) fp32
    const float* __restrict__ gam,
    const float* __restrict__ bet,
    float* __restrict__ out)              // (8,96,4096) fp32
{
    __shared__ float u_l[32 * 97];
    __shared__ float yt[32 * 192];
    __shared__ float ot[32 * 97];
    __shared__ float mu[32], rs[32];
    const int b = blockIdx.y, l0 = blockIdx.x * 32;
    const int tid = threadIdx.x;
    for (int idx = tid; idx < CDIM * 32; idx += 256) {
        int c = idx / 32, r = idx % 32;
        u_l[r * 97 + c] = x[((size_t)b * CDIM + c) * LSEQ + l0 + r];
    }
    for (int idx = tid; idx < 32 * 192; idx += 256)
        yt[idx] = b2f(yraw[((size_t)b * LSEQ + l0) * DIN + idx]);
    __syncthreads();
    // z-half in_proj GEMM (K=96) + silu gate applied to yt
    for (int idx = tid; idx < 32 * 48; idx += 256) {
        int row = idx / 48, cg = idx % 48;
        int col = cg * 4;
        const float4* w0 = (const float4*)(ipw + (size_t)(DIN + col + 0) * 96);
        const float4* w1 = (const float4*)(ipw + (size_t)(DIN + col + 1) * 96);
        const float4* w2 = (const float4*)(ipw + (size_t)(DIN + col + 2) * 96);
        const float4* w3 = (const float4*)(ipw + (size_t)(DIN + col + 3) * 96);
        const float* ur = &u_l[row * 97];
        float a0 = 0, a1 = 0, a2 = 0, a3 = 0;
        #pragma unroll
        for (int kk = 0; kk < 24; ++kk) {
            float uv[4];
            #pragma unroll
            for (int i = 0; i < 4; ++i) uv[i] = ur[kk * 4 + i];
            dot4(w0[kk], uv, a0);
            dot4(w1[kk], uv, a1);
            dot4(w2[kk], uv, a2);
            dot4(w3[kk], uv, a3);
        }
        yt[row * 192 + col + 0] *= silu_f(a0);
        yt[row * 192 + col + 1] *= silu_f(a1);
        yt[row * 192 + col + 2] *= silu_f(a2);
        yt[row * 192 + col + 3] *= silu_f(a3);
    }
    __syncthreads();
    // out_proj GEMM (K=192)
    for (int idx = tid; idx < 32 * 96; idx += 256) {
        int row = idx / 96, c = idx % 96;
        const float4* w = (const float4*)(opw + (size_t)c * DIN);
        const float* yr = &yt[row * 192];
        float acc = 0.0f;
        #pragma unroll
        for (int kk = 0; kk < 48; ++kk) {
            float uv[4];
            #pragma unroll
            for (int i = 0; i < 4; ++i) uv[i] = yr[kk * 4 + i];
            dot4(w[kk], uv, acc);
        }
        ot[row * 97 + c] = acc;
    }
    __syncthreads();
    if (tid < 32) {
        float s = 0.0f;
        for (int c = 0; c < 96; ++c) s += ot[tid * 97 + c];
        float mean = s * (1.0f / 96.0f);
        float v = 0.0f;
        for (int c = 0; c < 96; ++c) {
            float d = ot[tid * 97 + c] - mean;
            v = fmaf(d, d, v);
        }
        mu[tid] = mean;
        rs[tid] = rsqrtf(v * (1.0f / 96.0f) + 1e-5f);
    }
    __syncthreads();
    for (int idx = tid; idx < CDIM * 32; idx += 256) {
        int c = idx / 32, lr = idx % 32;
        float val = (ot[lr * 97 + c] - mu[lr]) * rs[lr] * gam[c] + bet[c];
        out[((size_t)b * CDIM + c) * LSEQ + l0 + lr] = val;
    }
}

extern "C" void kernel_launch(void* const* d_in, const int* in_sizes, int n_in,
                              void* d_out, int out_size, void* d_ws, size_t ws_size,
                              hipStream_t stream) {
    const float* x    = (const float*)d_in[0];
    const float* ipw  = (const float*)d_in[1];
    const float* cvw  = (const float*)d_in[2];
    const float* cvb  = (const float*)d_in[3];
    const float* xpw  = (const float*)d_in[4];
    const float* dpw  = (const float*)d_in[5];
    const float* dpb  = (const float*)d_in[6];
    const float* alog = (const float*)d_in[7];
    const float* Dp   = (const float*)d_in[8];
    const float* opw  = (const float*)d_in[9];
    const float* gam  = (const float*)d_in[10];
    const float* bet  = (const float*)d_in[11];
    float* out = (float*)d_out;

    // Workspace: ~30 MB total
    u16* xc    = (u16*)d_ws;                         // BL*192 bf16 = 12.6 MB
    float* dtb = (float*)(xc + (size_t)BL * DIN);    // BL*6  f32   = 0.8 MB
    float* bcb = dtb + (size_t)BL * DTR;             // BL*32 f32   = 4.2 MB
    float* ph  = bcb + (size_t)BL * 32;              // B*64*192*32 f32 = 12.6 MB

    k1_inproj_conv<<<dim3(LSEQ / 64, BATCH), 256, 0, stream>>>(x, ipw, cvw, cvb, xc);
    k2_xproj<<<dim3(BL / 4), 256, 0, stream>>>(xc, xpw, dtb, bcb);
    k3_scan_partial<<<dim3(NCHUNK, BATCH), 192, 0, stream>>>(xc, dtb, bcb, dpw, dpb, alog, ph);
    k4_combine<<<dim3(BATCH * 192 * DST / 256), 256, 0, stream>>>(ph);
    k5_scan_final<<<dim3(NCHUNK, BATCH), 192, 0, stream>>>(xc, dtb, bcb, dpw, dpb, alog, Dp, ph);
    k6_gate_outproj_ln<<<dim3(LSEQ / 32, BATCH), 256, 0, stream>>>(x, ipw, xc, opw, gam, bet, out);
}

// Round 4
// 473.532 us; speedup vs baseline: 2.5611x; 2.5611x over previous
//
#include <hip/hip_runtime.h>

#define BATCH   8
#define CDIM    96
#define LSEQ    4096
#define DIN     192
#define DTR     6
#define DST     16
#define NCHUNK  64
#define CLEN    64
#define BL      (BATCH*LSEQ)

typedef unsigned short u16;
typedef unsigned int   u32;

__device__ __forceinline__ float b2f(u16 u) {
    union { u32 i; float f; } v; v.i = ((u32)u) << 16; return v.f;
}
__device__ __forceinline__ u16 f2b(float f) {
    union { float f; u32 i; } v; v.f = f;
    u32 x = v.i;
    return (u16)((x + 0x7fffu + ((x >> 16) & 1u)) >> 16);
}
__device__ __forceinline__ float silu_f(float x) { return x / (1.0f + expf(-x)); }
__device__ __forceinline__ float softplus_f(float x) {
    return fmaxf(x, 0.0f) + log1pf(expf(-fabsf(x)));
}
__device__ __forceinline__ void fma4(const float4 w, const float4 u, float& acc) {
    acc = fmaf(w.x, u.x, acc);
    acc = fmaf(w.y, u.y, acc);
    acc = fmaf(w.z, u.z, acc);
    acc = fmaf(w.w, u.w, acc);
}

// K1: full in_proj (384 cols) + causal conv(4)+silu -> xc (bf16); silu(z) -> zs (bf16).
// grid (64, 8), block 256. Register-blocked GEMM: task = (4 cols x 16 rows),
// weights loaded once per task, reused x16 rows. LDS 52.5 KB -> 3 blocks/CU.
__global__ __launch_bounds__(256) void k1_inproj_conv(
    const float* __restrict__ x,    // (8,96,4096)
    const float* __restrict__ ipw,  // (384,96)
    const float* __restrict__ cvw,  // (192,4)
    const float* __restrict__ cvb,  // (192)
    u16* __restrict__ xc,           // (BL,192) silu(conv(xm))
    u16* __restrict__ zs)           // (BL,192) silu(z)
{
    __shared__ float u_lds[67 * 100];   // stride 100: 16B-aligned float4 rows
    __shared__ u16 xm_lds[67 * 192];
    const int b = blockIdx.y, l0 = blockIdx.x * 64, tid = threadIdx.x;

    for (int idx = tid; idx < CDIM * 67; idx += 256) {
        int c = idx / 67, row = idx % 67, l = l0 + row - 3;
        u_lds[row * 100 + c] = (l >= 0) ? x[((size_t)b * CDIM + c) * LSEQ + l] : 0.0f;
    }
    __syncthreads();

    // GEMM: 96 col-groups(4) x 5 row-chunks(16) = 480 tasks
    for (int t = tid; t < 480; t += 256) {
        int cg = t % 96, rc = t / 96, col = cg * 4, r0 = rc * 16;
        int rmax = (67 - r0 < 16) ? (67 - r0) : 16;
        float a0[16], a1[16], a2[16], a3[16];
        #pragma unroll
        for (int r = 0; r < 16; ++r) { a0[r] = a1[r] = a2[r] = a3[r] = 0.0f; }
        const float4* w0 = (const float4*)(ipw + (size_t)(col + 0) * 96);
        const float4* w1 = (const float4*)(ipw + (size_t)(col + 1) * 96);
        const float4* w2 = (const float4*)(ipw + (size_t)(col + 2) * 96);
        const float4* w3 = (const float4*)(ipw + (size_t)(col + 3) * 96);
        for (int kk = 0; kk < 24; ++kk) {
            float4 wa = w0[kk], wb = w1[kk], wc = w2[kk], wd = w3[kk];
            #pragma unroll
            for (int r = 0; r < 16; ++r) {
                if (r < rmax) {
                    float4 u4 = *(const float4*)&u_lds[(r0 + r) * 100 + kk * 4];
                    fma4(wa, u4, a0[r]);
                    fma4(wb, u4, a1[r]);
                    fma4(wc, u4, a2[r]);
                    fma4(wd, u4, a3[r]);
                }
            }
        }
        if (col < DIN) {
            for (int r = 0; r < rmax; ++r) {
                int row = r0 + r;
                u32 p0 = (u32)f2b(a0[r]) | ((u32)f2b(a1[r]) << 16);
                u32 p1 = (u32)f2b(a2[r]) | ((u32)f2b(a3[r]) << 16);
                *(uint2*)&xm_lds[row * 192 + col] = make_uint2(p0, p1);
            }
        } else {
            for (int r = 0; r < rmax; ++r) {
                int row = r0 + r;
                if (row >= 3) {
                    int l = l0 + row - 3;
                    u32 p0 = (u32)f2b(silu_f(a0[r])) | ((u32)f2b(silu_f(a1[r])) << 16);
                    u32 p1 = (u32)f2b(silu_f(a2[r])) | ((u32)f2b(silu_f(a3[r])) << 16);
                    *(uint2*)&zs[((size_t)b * LSEQ + l) * DIN + (col - DIN)] = make_uint2(p0, p1);
                }
            }
        }
    }
    __syncthreads();

    // causal conv(4) + bias + silu
    for (int idx = tid; idx < 64 * DIN; idx += 256) {
        int lr = idx / DIN, ch = idx % DIN;
        float acc = cvb[ch];
        acc = fmaf(cvw[ch * 4 + 0], b2f(xm_lds[(lr + 0) * 192 + ch]), acc);
        acc = fmaf(cvw[ch * 4 + 1], b2f(xm_lds[(lr + 1) * 192 + ch]), acc);
        acc = fmaf(cvw[ch * 4 + 2], b2f(xm_lds[(lr + 2) * 192 + ch]), acc);
        acc = fmaf(cvw[ch * 4 + 3], b2f(xm_lds[(lr + 3) * 192 + ch]), acc);
        xc[((size_t)b * LSEQ + l0 + lr) * DIN + ch] = f2b(silu_f(acc));
    }
}

// K2: x_proj as 64-row LDS-tiled GEMM. grid 512, block 256. LDS 54.4 KB.
// task = (2 cols x 4 rows); weights fp32 in LDS (stride 196 breaks bank aliasing).
__global__ __launch_bounds__(256) void k2_xproj(
    const u16* __restrict__ xc,
    const float* __restrict__ xpw,  // (38,192)
    float* __restrict__ dtb,        // (BL,6)
    float* __restrict__ bcb)        // (BL,32) [B(16) | C(16)]
{
    __shared__ u16 xcs[64 * 192];
    __shared__ float wl[38 * 196];
    const int tid = threadIdx.x;
    const size_t row0 = (size_t)blockIdx.x * 64;
    const u32* src = (const u32*)(xc + row0 * DIN);
    u32* dd = (u32*)xcs;
    for (int i = tid; i < 6144; i += 256) dd[i] = src[i];
    for (int i = tid; i < 38 * 192; i += 256) {
        int o = i / 192, k = i % 192;
        wl[o * 196 + k] = xpw[i];
    }
    __syncthreads();
    for (int t = tid; t < 304; t += 256) {   // 19 col-pairs x 16 row-chunks(4)
        int c2 = t % 19, rc = t / 19, o0 = c2 * 2, r0 = rc * 4;
        float a[4][2] = {};
        const float4* wA = (const float4*)(wl + o0 * 196);
        const float4* wB = (const float4*)(wl + (o0 + 1) * 196);
        const uint2* xp = (const uint2*)xcs;
        for (int k4 = 0; k4 < 48; ++k4) {
            float4 wa = wA[k4], wb = wB[k4];
            #pragma unroll
            for (int r = 0; r < 4; ++r) {
                uint2 u = xp[(r0 + r) * 48 + k4];
                float u0 = b2f((u16)(u.x & 0xffff)), u1 = b2f((u16)(u.x >> 16));
                float u2 = b2f((u16)(u.y & 0xffff)), u3 = b2f((u16)(u.y >> 16));
                a[r][0] = fmaf(u0, wa.x, fmaf(u1, wa.y, fmaf(u2, wa.z, fmaf(u3, wa.w, a[r][0]))));
                a[r][1] = fmaf(u0, wb.x, fmaf(u1, wb.y, fmaf(u2, wb.z, fmaf(u3, wb.w, a[r][1]))));
            }
        }
        for (int r = 0; r < 4; ++r) {
            size_t row = row0 + r0 + r;
            #pragma unroll
            for (int j = 0; j < 2; ++j) {
                int o = o0 + j;
                if (o < DTR) dtb[row * DTR + o] = a[r][j];
                else         bcb[row * 32 + (o - DTR)] = a[r][j];
            }
        }
    }
}

// K3 (pass A): chunk-local scan, xc tile staged in LDS. LDS 34.1 KB -> 4 blk/CU.
__global__ __launch_bounds__(192) void k3_scan_partial(
    const u16* __restrict__ xc,
    const float* __restrict__ dtbuf,
    const float* __restrict__ bcb,
    const float* __restrict__ dpw,   // (192,6)
    const float* __restrict__ dpb,   // (192)
    const float* __restrict__ alog,  // (192,16)
    float* __restrict__ ph)          // (B,NCHUNK,192,32) [P(16)|hend(16)]
{
    __shared__ float dts[CLEN * 6];
    __shared__ float bcs[CLEN * 32];
    __shared__ u16 xcs[CLEN * 192];
    const int b = blockIdx.y, s = blockIdx.x, e = threadIdx.x;
    const size_t rb = (size_t)b * LSEQ + s * CLEN;
    for (int i = e; i < CLEN * 6; i += 192)  dts[i] = dtbuf[rb * 6 + i];
    for (int i = e; i < CLEN * 32; i += 192) bcs[i] = bcb[rb * 32 + i];
    {
        const u32* src = (const u32*)(xc + rb * DIN);
        u32* dd = (u32*)xcs;
        for (int i = e; i < 6144; i += 192) dd[i] = src[i];
    }
    float wr[6];
    #pragma unroll
    for (int r = 0; r < 6; ++r) wr[r] = dpw[e * 6 + r];
    const float bias = dpb[e];
    float m[DST];
    #pragma unroll
    for (int n = 0; n < DST; ++n) m[n] = -expf(alog[e * DST + n]);
    float h[DST], P[DST];
    #pragma unroll
    for (int n = 0; n < DST; ++n) { h[n] = 0.0f; P[n] = 1.0f; }
    __syncthreads();
    for (int j = 0; j < CLEN; ++j) {
        float u = b2f(xcs[j * 192 + e]);
        float xdt = bias;
        #pragma unroll
        for (int r = 0; r < 6; ++r) xdt = fmaf(dts[j * 6 + r], wr[r], xdt);
        float delta = softplus_f(xdt);
        float du = delta * u;
        #pragma unroll
        for (int n = 0; n < DST; ++n) {
            float dA = expf(delta * m[n]);
            h[n] = fmaf(dA, h[n], du * bcs[j * 32 + n]);
            P[n] *= dA;
        }
    }
    float* o = ph + (((size_t)b * NCHUNK + s) * 192 + e) * 32;
    #pragma unroll
    for (int n = 0; n < DST; ++n) { o[n] = P[n]; o[16 + n] = h[n]; }
}

// K4 (pass B): sequential chunk combine; overwrites P-slot with chunk-start state.
__global__ __launch_bounds__(256) void k4_combine(float* __restrict__ ph)
{
    int g = blockIdx.x * 256 + threadIdx.x;
    int b = g / (192 * DST);
    int rem = g % (192 * DST);
    int e = rem / DST, n = rem % DST;
    float h = 0.0f;
    for (int s = 0; s < NCHUNK; ++s) {
        size_t ix = ((size_t)(b * NCHUNK + s) * 192 + e) * 32;
        float P = ph[ix + n];
        float hend = ph[ix + 16 + n];
        ph[ix + n] = h;
        h = fmaf(P, h, hend);
    }
}

// K5 (pass C): full scan with h_init; yraw = y + u*D written in-place over xc.
__global__ __launch_bounds__(192) void k5_scan_final(
    u16* __restrict__ xc,
    const float* __restrict__ dtbuf,
    const float* __restrict__ bcb,
    const float* __restrict__ dpw,
    const float* __restrict__ dpb,
    const float* __restrict__ alog,
    const float* __restrict__ Dp,
    const float* __restrict__ ph)
{
    __shared__ float dts[CLEN * 6];
    __shared__ float bcs[CLEN * 32];
    __shared__ u16 xcs[CLEN * 192];
    const int b = blockIdx.y, s = blockIdx.x, e = threadIdx.x;
    const size_t rb = (size_t)b * LSEQ + s * CLEN;
    for (int i = e; i < CLEN * 6; i += 192)  dts[i] = dtbuf[rb * 6 + i];
    for (int i = e; i < CLEN * 32; i += 192) bcs[i] = bcb[rb * 32 + i];
    {
        const u32* src = (const u32*)(xc + rb * DIN);
        u32* dd = (u32*)xcs;
        for (int i = e; i < 6144; i += 192) dd[i] = src[i];
    }
    float wr[6];
    #pragma unroll
    for (int r = 0; r < 6; ++r) wr[r] = dpw[e * 6 + r];
    const float bias = dpb[e];
    const float De = Dp[e];
    float m[DST];
    #pragma unroll
    for (int n = 0; n < DST; ++n) m[n] = -expf(alog[e * DST + n]);
    float h[DST];
    const float* hi = ph + (((size_t)b * NCHUNK + s) * 192 + e) * 32;
    #pragma unroll
    for (int n = 0; n < DST; ++n) h[n] = hi[n];
    __syncthreads();
    for (int j = 0; j < CLEN; ++j) {
        float u = b2f(xcs[j * 192 + e]);
        float xdt = bias;
        #pragma unroll
        for (int r = 0; r < 6; ++r) xdt = fmaf(dts[j * 6 + r], wr[r], xdt);
        float delta = softplus_f(xdt);
        float du = delta * u;
        float y = 0.0f;
        #pragma unroll
        for (int n = 0; n < DST; ++n) {
            float dA = expf(delta * m[n]);
            h[n] = fmaf(dA, h[n], du * bcs[j * 32 + n]);
            y = fmaf(h[n], bcs[j * 32 + 16 + n], y);
        }
        xc[(rb + j) * DIN + e] = f2b(y + u * De);
    }
}

// K6: gate (yraw*zs) + out_proj (register-blocked: 2 cols x 8 rows/task) +
// LayerNorm(96) + transposed store. grid (64,8), block 256. LDS 49.9 KB.
__global__ __launch_bounds__(256) void k6_gate_outproj_ln(
    const u16* __restrict__ yraw,   // (BL,192) bf16
    const u16* __restrict__ zsb,    // (BL,192) bf16
    const float* __restrict__ opw,  // (96,192)
    const float* __restrict__ gam,
    const float* __restrict__ bet,
    float* __restrict__ out)        // (8,96,4096)
{
    __shared__ u16 yt[64 * 192];
    __shared__ float ot[64 * 97];
    __shared__ float mu[64], rs[64];
    const int b = blockIdx.y, l0 = blockIdx.x * 64, tid = threadIdx.x;
    const size_t base = ((size_t)b * LSEQ + l0) * DIN;
    const u32* yr = (const u32*)(yraw + base);
    const u32* zr = (const u32*)(zsb + base);
    u32* ytu = (u32*)yt;
    for (int i = tid; i < 6144; i += 256) {
        u32 a = yr[i], z = zr[i];
        float y0 = b2f((u16)(a & 0xffff)) * b2f((u16)(z & 0xffff));
        float y1 = b2f((u16)(a >> 16)) * b2f((u16)(z >> 16));
        ytu[i] = (u32)f2b(y0) | ((u32)f2b(y1) << 16);
    }
    __syncthreads();
    for (int t = tid; t < 384; t += 256) {   // 48 col-pairs x 8 row-chunks(8)
        int c2 = t % 48, rc = t / 48, c0 = c2 * 2, r0 = rc * 8;
        float a[8][2] = {};
        const float4* wA = (const float4*)(opw + (size_t)c0 * DIN);
        const float4* wB = (const float4*)(opw + (size_t)(c0 + 1) * DIN);
        const uint2* yp = (const uint2*)yt;
        for (int k4 = 0; k4 < 48; ++k4) {
            float4 wa = wA[k4], wb = wB[k4];
            #pragma unroll
            for (int r = 0; r < 8; ++r) {
                uint2 u = yp[(r0 + r) * 48 + k4];
                float u0 = b2f((u16)(u.x & 0xffff)), u1 = b2f((u16)(u.x >> 16));
                float u2 = b2f((u16)(u.y & 0xffff)), u3 = b2f((u16)(u.y >> 16));
                a[r][0] = fmaf(u0, wa.x, fmaf(u1, wa.y, fmaf(u2, wa.z, fmaf(u3, wa.w, a[r][0]))));
                a[r][1] = fmaf(u0, wb.x, fmaf(u1, wb.y, fmaf(u2, wb.z, fmaf(u3, wb.w, a[r][1]))));
            }
        }
        #pragma unroll
        for (int r = 0; r < 8; ++r) {
            ot[(r0 + r) * 97 + c0 + 0] = a[r][0];
            ot[(r0 + r) * 97 + c0 + 1] = a[r][1];
        }
    }
    __syncthreads();
    if (tid < 64) {
        float s = 0.0f;
        for (int c = 0; c < 96; ++c) s += ot[tid * 97 + c];
        float mean = s * (1.0f / 96.0f);
        float v = 0.0f;
        for (int c = 0; c < 96; ++c) {
            float d = ot[tid * 97 + c] - mean;
            v = fmaf(d, d, v);
        }
        mu[tid] = mean;
        rs[tid] = rsqrtf(v * (1.0f / 96.0f) + 1e-5f);
    }
    __syncthreads();
    for (int idx = tid; idx < CDIM * 64; idx += 256) {
        int c = idx / 64, lr = idx % 64;
        float val = (ot[lr * 97 + c] - mu[lr]) * rs[lr] * gam[c] + bet[c];
        out[((size_t)b * CDIM + c) * LSEQ + l0 + lr] = val;
    }
}

extern "C" void kernel_launch(void* const* d_in, const int* in_sizes, int n_in,
                              void* d_out, int out_size, void* d_ws, size_t ws_size,
                              hipStream_t stream) {
    const float* x    = (const float*)d_in[0];
    const float* ipw  = (const float*)d_in[1];
    const float* cvw  = (const float*)d_in[2];
    const float* cvb  = (const float*)d_in[3];
    const float* xpw  = (const float*)d_in[4];
    const float* dpw  = (const float*)d_in[5];
    const float* dpb  = (const float*)d_in[6];
    const float* alog = (const float*)d_in[7];
    const float* Dp   = (const float*)d_in[8];
    const float* opw  = (const float*)d_in[9];
    const float* gam  = (const float*)d_in[10];
    const float* bet  = (const float*)d_in[11];
    float* out = (float*)d_out;

    // Workspace ~43 MB
    u16* xc    = (u16*)d_ws;                         // BL*192 bf16
    u16* zsb   = xc + (size_t)BL * DIN;              // BL*192 bf16
    float* dtb = (float*)(zsb + (size_t)BL * DIN);   // BL*6
    float* bcb = dtb + (size_t)BL * DTR;             // BL*32
    float* ph  = bcb + (size_t)BL * 32;              // B*64*192*32

    k1_inproj_conv<<<dim3(LSEQ / 64, BATCH), 256, 0, stream>>>(x, ipw, cvw, cvb, xc, zsb);
    k2_xproj<<<dim3(BL / 64), 256, 0, stream>>>(xc, xpw, dtb, bcb);
    k3_scan_partial<<<dim3(NCHUNK, BATCH), 192, 0, stream>>>(xc, dtb, bcb, dpw, dpb, alog, ph);
    k4_combine<<<dim3(BATCH * 192 * DST / 256), 256, 0, stream>>>(ph);
    k5_scan_final<<<dim3(NCHUNK, BATCH), 192, 0, stream>>>(xc, dtb, bcb, dpw, dpb, alog, Dp, ph);
    k6_gate_outproj_ln<<<dim3(LSEQ / 64, BATCH), 256, 0, stream>>>(xc, zsb, opw, gam, bet, out);
}